// Round 4
// baseline (5591.942 us; speedup 1.0000x reference)
//
#include <hip/hip_runtime.h>
#include <hip/hip_cooperative_groups.h>

namespace cg = cooperative_groups;

#define DTF   0.001f
#define NZV   250
#define NYV   350
#define NX    294          // 250 + 44
#define NYW   394          // 350 + 44
#define PADC  22
#define NSHOT 4
#define NTS   48
#define NRECV 100
#define NCELL (NX*NYW)     // 115836
#define NTOT  (NSHOT*NCELL)
#define XBL   22           // x in [0,21] is low band
#define XBH   (NX-22)      // 272: x >= 272 is high band
#define YBH   (NYW-22)     // 372
#define NB    44
#define PXSZ  (NSHOT*NB*NYW)   // x-band state: [shot][44][NYW]
#define PYSZ  (NSHOT*NX*NB)    // y-band state: [shot][NX][44]
#define NSB   ((NTOT+255)/256) // 1810 stencil blocks (fallback path)
#define GB    2                // gather blocks (fallback path)
#define NTHR  256

__device__ __forceinline__ int xbi(int i) {
    return ((unsigned)i < XBL) ? i : ((i >= XBH && i < NX) ? i-(NX-NB) : -1);
}
__device__ __forceinline__ int ybi(int j) {
    return ((unsigned)j < XBL) ? j : ((j >= YBH && j < NYW) ? j-(NYW-NB) : -1);
}
__device__ __forceinline__ float ldz(const float* __restrict__ w, int i, int j) {
    return ((unsigned)i < (unsigned)NX && (unsigned)j < (unsigned)NYW) ? w[i*NYW + j] : 0.f;
}
__device__ __forceinline__ float d1x(const float* __restrict__ w, int i, int j) {
    return (8.f*(ldz(w,i+1,j) - ldz(w,i-1,j)) - (ldz(w,i+2,j) - ldz(w,i-2,j))) * (1.f/60.f);
}
__device__ __forceinline__ float d1y(const float* __restrict__ w, int i, int j) {
    return (8.f*(ldz(w,i,j+1) - ldz(w,i,j-1)) - (ldz(w,i,j+2) - ldz(w,i,j-2))) * (1.f/60.f);
}
__device__ __forceinline__ float d2x(const float* __restrict__ w, int i, int j, float cc) {
    return (-(ldz(w,i+2,j)+ldz(w,i-2,j)) + 16.f*(ldz(w,i+1,j)+ldz(w,i-1,j)) - 30.f*cc) * (1.f/300.f);
}
__device__ __forceinline__ float d2y(const float* __restrict__ w, int i, int j, float cc) {
    return (-(ldz(w,i,j+2)+ldz(w,i,j-2)) + 16.f*(ldz(w,i,j+1)+ldz(w,i,j-1)) - 30.f*cc) * (1.f/300.f);
}
__device__ __forceinline__ void prof1(int x, int n, float d, float vmax, float* a, float* b) {
    float fl = fminf(fmaxf((float)(2 + 20 - x)/20.f, 0.f), 1.f);
    float fh = fminf(fmaxf((float)(x - (n - 23))/20.f, 0.f), 1.f);
    float fr = fmaxf(fl, fh);
    float sigma = 3.f*vmax*logf(1000.f)/(2.f*20.f*d)*fr*fr;
    float alpha = 3.14159265358979f*25.f*(1.f - fr);
    float bb = expf(-(sigma+alpha)*DTF);
    *a = sigma/(sigma+alpha+1e-9f)*(bb-1.f);
    *b = bb;
}

// Fused per-cell update used by both paths. Returns nothing; writes wpb/scpb
// (own cell), pxn/pyn/pxsn/pysn (own band cell), zx/zy/zxs/zys (own band cell).
__device__ __forceinline__ void cell_update(
    int c, int t,
    const float* __restrict__ wcb, float* __restrict__ wpb,
    const float* __restrict__ sccb, float* __restrict__ scpb,
    const float* __restrict__ pxc, float* __restrict__ pxn,
    const float* __restrict__ pyc, float* __restrict__ pyn,
    const float* __restrict__ pxsc, float* __restrict__ pxsn,
    const float* __restrict__ pysc, float* __restrict__ pysn,
    float* __restrict__ zx, float* __restrict__ zy,
    float* __restrict__ zxs, float* __restrict__ zys,
    const float* __restrict__ v2, const float* __restrict__ st,
    const float* __restrict__ axv, const float* __restrict__ bxv,
    const float* __restrict__ ayv, const float* __restrict__ byv,
    const float* __restrict__ amp, const int* __restrict__ sloc)
{
    int s = c / NCELL; int r = c - s*NCELL;
    int i = r / NYW;   int j = r - i*NYW;
    const float* w  = wcb  + s*NCELL;
    const float* ww = sccb + s*NCELL;

    float wcv  = w[r];
    float wscv = ww[r];

    float tx  = d2x(w,  i, j, wcv);
    float txs = d2x(ww, i, j, wscv);
    float ty  = d2y(w,  i, j, wcv);
    float tys = d2y(ww, i, j, wscv);

    int ib = xbi(i);
    int jb = ybi(j);

    if (i <= XBL+1 || i >= XBH-2) {
        float pv[5], pvs[5];
        #pragma unroll
        for (int k = 0; k < 5; ++k) {
            int ik = i + k - 2; int b = xbi(ik);
            float p = 0.f, ps = 0.f;
            if (b >= 0) {
                float bxk = bxv[ik], axk = axv[ik];
                int o = (s*NB + b)*NYW + j;
                p  = bxk*pxc[o]  + axk*d1x(w,  ik, j);
                ps = bxk*pxsc[o] + axk*d1x(ww, ik, j);
            }
            pv[k] = p; pvs[k] = ps;
        }
        tx  += (8.f*(pv[3]-pv[1])  - (pv[4]-pv[0]))  * (1.f/60.f);
        txs += (8.f*(pvs[3]-pvs[1]) - (pvs[4]-pvs[0])) * (1.f/60.f);
        if (ib >= 0) {
            int o = (s*NB + ib)*NYW + j;
            pxn[o] = pv[2]; pxsn[o] = pvs[2];
        }
    }

    if (j <= XBL+1 || j >= YBH-2) {
        float pv[5], pvs[5];
        #pragma unroll
        for (int k = 0; k < 5; ++k) {
            int jk = j + k - 2; int b = ybi(jk);
            float p = 0.f, ps = 0.f;
            if (b >= 0) {
                float byk = byv[jk], ayk = ayv[jk];
                int o = (s*NX + i)*NB + b;
                p  = byk*pyc[o]  + ayk*d1y(w,  i, jk);
                ps = byk*pysc[o] + ayk*d1y(ww, i, jk);
            }
            pv[k] = p; pvs[k] = ps;
        }
        ty  += (8.f*(pv[3]-pv[1])  - (pv[4]-pv[0]))  * (1.f/60.f);
        tys += (8.f*(pvs[3]-pvs[1]) - (pvs[4]-pvs[0])) * (1.f/60.f);
        if (jb >= 0) {
            int o = (s*NX + i)*NB + jb;
            pyn[o] = pv[2]; pysn[o] = pvs[2];
        }
    }

    float zxv = 0.f, zyv = 0.f, zxsv = 0.f, zysv = 0.f;
    if (ib >= 0) {
        int o = (s*NB + ib)*NYW + j;
        float bx = bxv[i], ax = axv[i];
        zxv  = bx*zx[o]  + ax*tx;  zx[o]  = zxv;
        zxsv = bx*zxs[o] + ax*txs; zxs[o] = zxsv;
    }
    if (jb >= 0) {
        int o = (s*NX + i)*NB + jb;
        float by = byv[j], ay = ayv[j];
        zyv  = by*zy[o]  + ay*ty;  zy[o]  = zyv;
        zysv = by*zys[o] + ay*tys; zys[o] = zysv;
    }

    float lap  = tx + zxv + ty + zyv;
    float laps = txs + zxsv + tys + zysv;
    float vd   = v2[r];
    float wn   = vd*lap + 2.f*wcv - wpb[c];
    if (i == sloc[s*2] + PADC && j == sloc[s*2+1] + PADC)
        wn += vd * amp[s*NTS + t];
    float wsn = vd*laps + 2.f*wscv - scpb[c] + st[r]*lap;
    wpb[c]  = wn;
    scpb[c] = wsn;
}

struct SimArgs {
    const float* v; const float* scat; const float* amp;
    const int* sloc; const int* rloc;
    float* out; float* ws;
};

// ================= cooperative single-kernel path =================
__global__ __launch_bounds__(NTHR, 2) void k_sim(SimArgs A) {
    cg::grid_group grid = cg::this_grid();
    const int tid = blockIdx.x*NTHR + threadIdx.x;
    const int nth = gridDim.x*NTHR;

    float* ws = A.ws;
    const size_t F = (size_t)NTOT;
    float* wA   = ws;
    float* wB   = wA + F;
    float* sA   = wB + F;
    float* sB   = sA + F;
    float* pxA  = sB + F;
    float* pxB  = pxA + PXSZ;
    float* pxsA = pxB + PXSZ;
    float* pxsB = pxsA + PXSZ;
    float* zx   = pxsB + PXSZ;
    float* zxs  = zx + PXSZ;
    float* pyA  = zxs + PXSZ;
    float* pyB  = pyA + PYSZ;
    float* pysA = pyB + PYSZ;
    float* pysB = pysA + PYSZ;
    float* zy   = pysB + PYSZ;
    float* zys  = zy + PYSZ;
    float* vmxf = zys + PYSZ;
    float* v2   = vmxf + 1;
    float* st   = v2 + NCELL;
    float* axv  = st + NCELL;
    float* bxv  = axv + NX;
    float* ayv  = bxv + NX;
    float* byv  = ayv + NYW;
    unsigned* vmx = (unsigned*)vmxf;

    // phase 0: zero recurrence state + vmax accumulator
    const size_t ZTOT = 4*F + 6*(size_t)PXSZ + 6*(size_t)PYSZ + 1;
    for (size_t z = (size_t)tid; z < ZTOT; z += (size_t)nth) ws[z] = 0.f;
    grid.sync();

    // phase 1: vmax
    {
        float m = 0.f;
        for (int idx = tid; idx < NZV*NYV; idx += nth) m = fmaxf(m, fabsf(A.v[idx]));
        __shared__ float sm[NTHR];
        sm[threadIdx.x] = m; __syncthreads();
        for (int o = NTHR/2; o > 0; o >>= 1) {
            if (threadIdx.x < o) sm[threadIdx.x] = fmaxf(sm[threadIdx.x], sm[threadIdx.x+o]);
            __syncthreads();
        }
        if (threadIdx.x == 0) atomicMax(vmx, __float_as_uint(sm[0]));
    }
    grid.sync();

    // phase 2: PML profiles + v2dt2/sterm
    {
        float vmax = __uint_as_float(*vmx);
        if (tid < NX) prof1(tid, NX, 5.0f, vmax, &axv[tid], &bxv[tid]);
        else if (tid < NX + NYW) { int y = tid - NX; prof1(y, NYW, 5.0f, vmax, &ayv[y], &byv[y]); }
        for (int c = tid; c < NCELL; c += nth) {
            int i = c / NYW, j = c - (c / NYW)*NYW;
            int iz = min(max(i - PADC, 0), NZV-1);
            int iy = min(max(j - PADC, 0), NYV-1);
            float vv = A.v[iz*NYV + iy];
            v2[c] = vv*vv*(DTF*DTF);
            float sp = 0.f;
            if (i >= PADC && i < PADC+NZV && j >= PADC && j < PADC+NYV)
                sp = A.scat[(i-PADC)*NYV + (j-PADC)];
            st[c] = 2.f*vv*sp*(DTF*DTF);
        }
    }
    grid.sync();

    // time loop: one grid.sync per step
    float *wcb=wA, *wpb=wB, *sccb=sA, *scpb=sB;
    float *pxc=pxA, *pxn=pxB, *pxsc=pxsA, *pxsn=pxsB;
    float *pyc=pyA, *pyn=pyB, *pysc=pysA, *pysn=pysB;

    for (int t = 0; t < NTS; ++t) {
        for (int c = tid; c < NTOT; c += nth)
            cell_update(c, t, wcb, wpb, sccb, scpb,
                        pxc, pxn, pyc, pyn, pxsc, pxsn, pysc, pysn,
                        zx, zy, zxs, zys, v2, st, axv, bxv, ayv, byv,
                        A.amp, A.sloc);
        grid.sync();

        if (tid < NSHOT*NRECV) {
            int s = tid / NRECV, rr = tid - s*NRECV;
            int ri = A.rloc[(s*NRECV+rr)*2+0] + PADC;
            int rj = A.rloc[(s*NRECV+rr)*2+1] + PADC;
            A.out[(s*NRECV+rr)*NTS + t] = scpb[s*NCELL + ri*NYW + rj];
        }

        float* tm;
        tm=wcb;  wcb=wpb;   wpb=tm;
        tm=sccb; sccb=scpb; scpb=tm;
        tm=pxc;  pxc=pxn;   pxn=tm;
        tm=pyc;  pyc=pyn;   pyn=tm;
        tm=pxsc; pxsc=pxsn; pxsn=tm;
        tm=pysc; pysc=pysn; pysn=tm;
    }
}

// ================= fallback multi-kernel path (verified round-2) =================
__global__ void k_vmax(const float* __restrict__ v, unsigned* __restrict__ vmx) {
    __shared__ float sm[256];
    float m = 0.f;
    for (int idx = blockIdx.x*256 + threadIdx.x; idx < NZV*NYV; idx += gridDim.x*256)
        m = fmaxf(m, fabsf(v[idx]));
    sm[threadIdx.x] = m; __syncthreads();
    for (int o = 128; o > 0; o >>= 1) {
        if (threadIdx.x < o) sm[threadIdx.x] = fmaxf(sm[threadIdx.x], sm[threadIdx.x+o]);
        __syncthreads();
    }
    if (threadIdx.x == 0) atomicMax(vmx, __float_as_uint(sm[0]));
}

__global__ void k_prep(const float* __restrict__ v, const float* __restrict__ sc,
                       float* __restrict__ v2dt2, float* __restrict__ sterm) {
    int c = blockIdx.x*blockDim.x + threadIdx.x;
    if (c >= NCELL) return;
    int i = c / NYW, j = c - (c / NYW)*NYW;
    int iz = min(max(i - PADC, 0), NZV-1);
    int iy = min(max(j - PADC, 0), NYV-1);
    float vv = v[iz*NYV + iy];
    v2dt2[c] = vv*vv*(DTF*DTF);
    float sp = 0.f;
    if (i >= PADC && i < PADC+NZV && j >= PADC && j < PADC+NYV)
        sp = sc[(i-PADC)*NYV + (j-PADC)];
    sterm[c] = 2.f*vv*sp*(DTF*DTF);
}

__global__ void k_prof(const unsigned* __restrict__ vmx,
                       float* __restrict__ axv, float* __restrict__ bxv,
                       float* __restrict__ ayv, float* __restrict__ byv) {
    int x = threadIdx.x;
    float vmax = __uint_as_float(vmx[0]);
    if (x < NX)  prof1(x, NX,  5.0f, vmax, &axv[x], &bxv[x]);
    if (x < NYW) prof1(x, NYW, 5.0f, vmax, &ayv[x], &byv[x]);
}

__global__ __launch_bounds__(256) void k_fstep(
    const float* __restrict__ wf,   float* __restrict__ wold,
    const float* __restrict__ wsf,  float* __restrict__ wsold,
    const float* __restrict__ pxo,  float* __restrict__ pxn,
    const float* __restrict__ pyo,  float* __restrict__ pyn,
    const float* __restrict__ pxso, float* __restrict__ pxsn,
    const float* __restrict__ pyso, float* __restrict__ pysn,
    float* __restrict__ zx,  float* __restrict__ zy,
    float* __restrict__ zxs, float* __restrict__ zys,
    const float* __restrict__ v2, const float* __restrict__ st,
    const float* __restrict__ axv, const float* __restrict__ bxv,
    const float* __restrict__ ayv, const float* __restrict__ byv,
    const float* __restrict__ amp, const int* __restrict__ sloc,
    const int* __restrict__ rloc, float* __restrict__ out, int t)
{
    int bid = blockIdx.x;
    if (bid >= NSB) {
        if (t == 0) return;
        int g = (bid - NSB)*256 + threadIdx.x;
        if (g >= NSHOT*NRECV) return;
        int s = g / NRECV, rr = g - s*NRECV;
        int ri = rloc[(s*NRECV+rr)*2+0] + PADC;
        int rj = rloc[(s*NRECV+rr)*2+1] + PADC;
        out[(s*NRECV+rr)*NTS + (t-1)] = wsf[s*NCELL + ri*NYW + rj];
        return;
    }
    int c = bid*256 + threadIdx.x;
    if (c >= NTOT) return;
    cell_update(c, t, wf, wold, wsf, wsold,
                pxo, pxn, pyo, pyn, pxso, pxsn, pyso, pysn,
                zx, zy, zxs, zys, v2, st, axv, bxv, ayv, byv, amp, sloc);
}

__global__ void k_gtail(const float* __restrict__ wsn, const int* __restrict__ rloc,
                        float* __restrict__ out) {
    int g = blockIdx.x*blockDim.x + threadIdx.x;
    if (g >= NSHOT*NRECV) return;
    int s = g / NRECV, rr = g - s*NRECV;
    int ri = rloc[(s*NRECV+rr)*2+0] + PADC;
    int rj = rloc[(s*NRECV+rr)*2+1] + PADC;
    out[(s*NRECV+rr)*NTS + (NTS-1)] = wsn[s*NCELL + ri*NYW + rj];
}

extern "C" void kernel_launch(void* const* d_in, const int* in_sizes, int n_in,
                              void* d_out, int out_size, void* d_ws, size_t ws_size,
                              hipStream_t stream) {
    const float* v    = (const float*)d_in[0];
    const float* scat = (const float*)d_in[1];
    const float* amp  = (const float*)d_in[2];
    const int*   sloc = (const int*)d_in[3];
    const int*   rloc = (const int*)d_in[4];
    float* out = (float*)d_out;
    float* ws  = (float*)d_ws;

    SimArgs args;
    args.v = v; args.scat = scat; args.amp = amp;
    args.sloc = sloc; args.rloc = rloc;
    args.out = out; args.ws = ws;

    // ---- preferred: single cooperative kernel, grid clamped to occupancy
    int maxb = 0;
    int nblk = 512;
    if (hipOccupancyMaxActiveBlocksPerMultiprocessor(&maxb, (const void*)k_sim, NTHR, 0)
            == hipSuccess && maxb > 0) {
        long cap = (long)maxb * 256;   // 256 CUs on MI355X
        nblk = (int)(cap < 1024 ? cap : 1024);
    }
    if (nblk < 1) nblk = 1;
    void* kargs[] = { &args };
    hipError_t e = hipLaunchCooperativeKernel((const void*)k_sim, dim3(nblk), dim3(NTHR),
                                              kargs, 0, stream);
    if (e == hipSuccess) return;

    // ---- fallback: verified multi-kernel path
    const size_t F = (size_t)NTOT;
    float* wA   = ws;
    float* wB   = wA + F;
    float* sA   = wB + F;
    float* sB   = sA + F;
    float* pxA  = sB + F;
    float* pxB  = pxA + PXSZ;
    float* pxsA = pxB + PXSZ;
    float* pxsB = pxsA + PXSZ;
    float* zx   = pxsB + PXSZ;
    float* zxs  = zx + PXSZ;
    float* pyA  = zxs + PXSZ;
    float* pyB  = pyA + PYSZ;
    float* pysA = pyB + PYSZ;
    float* pysB = pysA + PYSZ;
    float* zy   = pysB + PYSZ;
    float* zys  = zy + PYSZ;
    float* vmxf = zys + PYSZ;
    float* v2   = vmxf + 1;
    float* st   = v2 + NCELL;
    float* axv  = st + NCELL;
    float* bxv  = axv + NX;
    float* ayv  = bxv + NX;
    float* byv  = ayv + NYW;
    unsigned* vmx = (unsigned*)vmxf;

    size_t zero_floats = 4*F + 6*(size_t)PXSZ + 6*(size_t)PYSZ + 1;
    hipMemsetAsync(ws, 0, zero_floats*sizeof(float), stream);

    hipLaunchKernelGGL(k_vmax, dim3(64), dim3(256), 0, stream, v, vmx);
    hipLaunchKernelGGL(k_prep, dim3((NCELL+255)/256), dim3(256), 0, stream, v, scat, v2, st);
    hipLaunchKernelGGL(k_prof, dim3(1), dim3(512), 0, stream, vmx, axv, bxv, ayv, byv);

    float* wc  = wA;  float* wp  = wB;
    float* scc = sA;  float* scp = sB;
    float* pxc = pxA; float* pxn = pxB;
    float* pyc = pyA; float* pyn = pyB;
    float* pxsc = pxsA; float* pxsn = pxsB;
    float* pysc = pysA; float* pysn = pysB;

    for (int t = 0; t < NTS; ++t) {
        hipLaunchKernelGGL(k_fstep, dim3(NSB + GB), dim3(256), 0, stream,
                           wc, wp, scc, scp,
                           pxc, pxn, pyc, pyn, pxsc, pxsn, pysc, pysn,
                           zx, zy, zxs, zys,
                           v2, st, axv, bxv, ayv, byv,
                           amp, sloc, rloc, out, t);
        float* tmp;
        tmp = wc;  wc  = wp;  wp  = tmp;
        tmp = scc; scc = scp; scp = tmp;
        tmp = pxc; pxc = pxn; pxn = tmp;
        tmp = pyc; pyc = pyn; pyn = tmp;
        tmp = pxsc; pxsc = pxsn; pxsn = tmp;
        tmp = pysc; pysc = pysn; pysn = tmp;
    }
    hipLaunchKernelGGL(k_gtail, dim3(2), dim3(256), 0, stream, scc, rloc, out);
}

// Round 5
// 2740.587 us; speedup vs baseline: 2.0404x; 2.0404x over previous
//
#include <hip/hip_runtime.h>

#define DTF   0.001f
#define NZV   250
#define NYV   350
#define NX    294          // 250 + 44
#define NYW   394          // 350 + 44
#define PADC  22
#define NSHOT 4
#define NTS   48
#define NRECV 100
#define NCELL (NX*NYW)     // 115836
#define NTOT  (NSHOT*NCELL)
#define XBL   22           // x in [0,21] is low band
#define XBH   (NX-22)      // 272: x >= 272 is high band
#define YBH   (NYW-22)     // 372
#define NB    44
#define PXSZ  (NSHOT*NB*NYW)   // x-band state: [shot][44][NYW]
#define PYSZ  (NSHOT*NX*NB)    // y-band state: [shot][NX][44]
#define NSB   ((NTOT+255)/256) // fallback stencil blocks
#define GB    2                // fallback gather blocks
#define NTHR  256
#define NBLK  1024
#define NGRP  32
#define GSZ   (NBLK/NGRP)      // 32
#define BARF  1024             // floats reserved at ws head for barrier+vmx

__device__ __forceinline__ int xbi(int i) {
    return ((unsigned)i < XBL) ? i : ((i >= XBH && i < NX) ? i-(NX-NB) : -1);
}
__device__ __forceinline__ int ybi(int j) {
    return ((unsigned)j < XBL) ? j : ((j >= YBH && j < NYW) ? j-(NYW-NB) : -1);
}
__device__ __forceinline__ float ldz(const float* __restrict__ w, int i, int j) {
    return ((unsigned)i < (unsigned)NX && (unsigned)j < (unsigned)NYW) ? w[i*NYW + j] : 0.f;
}
__device__ __forceinline__ float d1x(const float* __restrict__ w, int i, int j) {
    return (8.f*(ldz(w,i+1,j) - ldz(w,i-1,j)) - (ldz(w,i+2,j) - ldz(w,i-2,j))) * (1.f/60.f);
}
__device__ __forceinline__ float d1y(const float* __restrict__ w, int i, int j) {
    return (8.f*(ldz(w,i,j+1) - ldz(w,i,j-1)) - (ldz(w,i,j+2) - ldz(w,i,j-2))) * (1.f/60.f);
}
__device__ __forceinline__ float d2x(const float* __restrict__ w, int i, int j, float cc) {
    return (-(ldz(w,i+2,j)+ldz(w,i-2,j)) + 16.f*(ldz(w,i+1,j)+ldz(w,i-1,j)) - 30.f*cc) * (1.f/300.f);
}
__device__ __forceinline__ float d2y(const float* __restrict__ w, int i, int j, float cc) {
    return (-(ldz(w,i,j+2)+ldz(w,i,j-2)) + 16.f*(ldz(w,i,j+1)+ldz(w,i,j-1)) - 30.f*cc) * (1.f/300.f);
}
__device__ __forceinline__ void prof1(int x, int n, float d, float vmax, float* a, float* b) {
    float fl = fminf(fmaxf((float)(2 + 20 - x)/20.f, 0.f), 1.f);
    float fh = fminf(fmaxf((float)(x - (n - 23))/20.f, 0.f), 1.f);
    float fr = fmaxf(fl, fh);
    float sigma = 3.f*vmax*logf(1000.f)/(2.f*20.f*d)*fr*fr;
    float alpha = 3.14159265358979f*25.f*(1.f - fr);
    float bb = expf(-(sigma+alpha)*DTF);
    *a = sigma/(sigma+alpha+1e-9f)*(bb-1.f);
    *b = bb;
}

// Fused per-cell update (verified in rounds 2 and 4).
__device__ __forceinline__ void cell_update(
    int c, int t,
    const float* __restrict__ wcb, float* __restrict__ wpb,
    const float* __restrict__ sccb, float* __restrict__ scpb,
    const float* __restrict__ pxc, float* __restrict__ pxn,
    const float* __restrict__ pyc, float* __restrict__ pyn,
    const float* __restrict__ pxsc, float* __restrict__ pxsn,
    const float* __restrict__ pysc, float* __restrict__ pysn,
    float* __restrict__ zx, float* __restrict__ zy,
    float* __restrict__ zxs, float* __restrict__ zys,
    const float* __restrict__ v2, const float* __restrict__ st,
    const float* __restrict__ axv, const float* __restrict__ bxv,
    const float* __restrict__ ayv, const float* __restrict__ byv,
    const float* __restrict__ amp, const int* __restrict__ sloc)
{
    int s = c / NCELL; int r = c - s*NCELL;
    int i = r / NYW;   int j = r - i*NYW;
    const float* w  = wcb  + s*NCELL;
    const float* ww = sccb + s*NCELL;

    float wcv  = w[r];
    float wscv = ww[r];

    float tx  = d2x(w,  i, j, wcv);
    float txs = d2x(ww, i, j, wscv);
    float ty  = d2y(w,  i, j, wcv);
    float tys = d2y(ww, i, j, wscv);

    int ib = xbi(i);
    int jb = ybi(j);

    if (i <= XBL+1 || i >= XBH-2) {
        float pv[5], pvs[5];
        #pragma unroll
        for (int k = 0; k < 5; ++k) {
            int ik = i + k - 2; int b = xbi(ik);
            float p = 0.f, ps = 0.f;
            if (b >= 0) {
                float bxk = bxv[ik], axk = axv[ik];
                int o = (s*NB + b)*NYW + j;
                p  = bxk*pxc[o]  + axk*d1x(w,  ik, j);
                ps = bxk*pxsc[o] + axk*d1x(ww, ik, j);
            }
            pv[k] = p; pvs[k] = ps;
        }
        tx  += (8.f*(pv[3]-pv[1])  - (pv[4]-pv[0]))  * (1.f/60.f);
        txs += (8.f*(pvs[3]-pvs[1]) - (pvs[4]-pvs[0])) * (1.f/60.f);
        if (ib >= 0) {
            int o = (s*NB + ib)*NYW + j;
            pxn[o] = pv[2]; pxsn[o] = pvs[2];
        }
    }

    if (j <= XBL+1 || j >= YBH-2) {
        float pv[5], pvs[5];
        #pragma unroll
        for (int k = 0; k < 5; ++k) {
            int jk = j + k - 2; int b = ybi(jk);
            float p = 0.f, ps = 0.f;
            if (b >= 0) {
                float byk = byv[jk], ayk = ayv[jk];
                int o = (s*NX + i)*NB + b;
                p  = byk*pyc[o]  + ayk*d1y(w,  i, jk);
                ps = byk*pysc[o] + ayk*d1y(ww, i, jk);
            }
            pv[k] = p; pvs[k] = ps;
        }
        ty  += (8.f*(pv[3]-pv[1])  - (pv[4]-pv[0]))  * (1.f/60.f);
        tys += (8.f*(pvs[3]-pvs[1]) - (pvs[4]-pvs[0])) * (1.f/60.f);
        if (jb >= 0) {
            int o = (s*NX + i)*NB + jb;
            pyn[o] = pv[2]; pysn[o] = pvs[2];
        }
    }

    float zxv = 0.f, zyv = 0.f, zxsv = 0.f, zysv = 0.f;
    if (ib >= 0) {
        int o = (s*NB + ib)*NYW + j;
        float bx = bxv[i], ax = axv[i];
        zxv  = bx*zx[o]  + ax*tx;  zx[o]  = zxv;
        zxsv = bx*zxs[o] + ax*txs; zxs[o] = zxsv;
    }
    if (jb >= 0) {
        int o = (s*NX + i)*NB + jb;
        float by = byv[j], ay = ayv[j];
        zyv  = by*zy[o]  + ay*ty;  zy[o]  = zyv;
        zysv = by*zys[o] + ay*tys; zys[o] = zysv;
    }

    float lap  = tx + zxv + ty + zyv;
    float laps = txs + zxsv + tys + zysv;
    float vd   = v2[r];
    float wn   = vd*lap + 2.f*wcv - wpb[c];
    if (i == sloc[s*2] + PADC && j == sloc[s*2+1] + PADC)
        wn += vd * amp[s*NTS + t];
    float wsn = vd*laps + 2.f*wscv - scpb[c] + st[r]*lap;
    wpb[c]  = wn;
    scpb[c] = wsn;
}

// ---- custom 2-level grid barrier ----
// layout in bar (uints): grp[32*16] (0..511), root at 512, gen at 528, vmx at 544
__device__ __forceinline__ void gbar(unsigned* bar, unsigned target) {
    __syncthreads();
    if (threadIdx.x == 0) {
        unsigned* grp  = bar;
        unsigned* root = bar + NGRP*16;
        unsigned* gen  = bar + NGRP*16 + 16;
        int g = blockIdx.x & (NGRP-1);
        unsigned old = __hip_atomic_fetch_add(&grp[g*16], 1u, __ATOMIC_ACQ_REL,
                                              __HIP_MEMORY_SCOPE_AGENT);
        if (old == (unsigned)(GSZ-1)) {
            unsigned r = __hip_atomic_fetch_add(root, 1u, __ATOMIC_ACQ_REL,
                                                __HIP_MEMORY_SCOPE_AGENT);
            if (r == (unsigned)(NGRP-1)) {
                #pragma unroll
                for (int k = 0; k < NGRP; ++k)
                    __hip_atomic_store(&grp[k*16], 0u, __ATOMIC_RELAXED,
                                       __HIP_MEMORY_SCOPE_AGENT);
                __hip_atomic_store(root, 0u, __ATOMIC_RELAXED,
                                   __HIP_MEMORY_SCOPE_AGENT);
                __hip_atomic_store(gen, target, __ATOMIC_RELEASE,
                                   __HIP_MEMORY_SCOPE_AGENT);
            }
        }
        while (__hip_atomic_load(gen, __ATOMIC_RELAXED,
                                 __HIP_MEMORY_SCOPE_AGENT) < target)
            __builtin_amdgcn_s_sleep(8);
        __builtin_amdgcn_fence(__ATOMIC_ACQUIRE, "agent");
    }
    __syncthreads();
}

struct SimArgs {
    const float* v; const float* scat; const float* amp;
    const int* sloc; const int* rloc;
    float* out; float* ws;
};

// ================= persistent single-kernel path =================
__global__ __launch_bounds__(NTHR, 2) void k_sim(SimArgs A) {
    const int tid = blockIdx.x*NTHR + threadIdx.x;
    const int nth = gridDim.x*NTHR;

    unsigned* bar = (unsigned*)A.ws;
    unsigned* vmx = bar + 544;

    float* base = A.ws + BARF;
    const size_t F = (size_t)NTOT;
    float* wA   = base;
    float* wB   = wA + F;
    float* sA   = wB + F;
    float* sB   = sA + F;
    float* pxA  = sB + F;
    float* pxB  = pxA + PXSZ;
    float* pxsA = pxB + PXSZ;
    float* pxsB = pxsA + PXSZ;
    float* zx   = pxsB + PXSZ;
    float* zxs  = zx + PXSZ;
    float* pyA  = zxs + PXSZ;
    float* pyB  = pyA + PYSZ;
    float* pysA = pyB + PYSZ;
    float* pysB = pysA + PYSZ;
    float* zy   = pysB + PYSZ;
    float* zys  = zy + PYSZ;
    float* v2   = zys + PYSZ;
    float* st   = v2 + NCELL;
    float* axv  = st + NCELL;
    float* bxv  = axv + NX;
    float* ayv  = bxv + NX;
    float* byv  = ayv + NYW;

    unsigned bn = 0;

    // phase 0: zero recurrence state (barrier region zeroed by host memset)
    const size_t ZTOT = 4*F + 6*(size_t)PXSZ + 6*(size_t)PYSZ;
    for (size_t z = (size_t)tid; z < ZTOT; z += (size_t)nth) base[z] = 0.f;
    gbar(bar, ++bn);

    // phase 1: vmax
    {
        float m = 0.f;
        for (int idx = tid; idx < NZV*NYV; idx += nth) m = fmaxf(m, fabsf(A.v[idx]));
        __shared__ float sm[NTHR];
        sm[threadIdx.x] = m; __syncthreads();
        for (int o = NTHR/2; o > 0; o >>= 1) {
            if (threadIdx.x < o) sm[threadIdx.x] = fmaxf(sm[threadIdx.x], sm[threadIdx.x+o]);
            __syncthreads();
        }
        if (threadIdx.x == 0) atomicMax(vmx, __float_as_uint(sm[0]));
    }
    gbar(bar, ++bn);

    // phase 2: PML profiles + v2dt2/sterm
    {
        float vmax = __uint_as_float(__hip_atomic_load(vmx, __ATOMIC_RELAXED,
                                                       __HIP_MEMORY_SCOPE_AGENT));
        if (tid < NX) prof1(tid, NX, 5.0f, vmax, &axv[tid], &bxv[tid]);
        else if (tid < NX + NYW) { int y = tid - NX; prof1(y, NYW, 5.0f, vmax, &ayv[y], &byv[y]); }
        for (int c = tid; c < NCELL; c += nth) {
            int i = c / NYW, j = c - (c / NYW)*NYW;
            int iz = min(max(i - PADC, 0), NZV-1);
            int iy = min(max(j - PADC, 0), NYV-1);
            float vv = A.v[iz*NYV + iy];
            v2[c] = vv*vv*(DTF*DTF);
            float sp = 0.f;
            if (i >= PADC && i < PADC+NZV && j >= PADC && j < PADC+NYV)
                sp = A.scat[(i-PADC)*NYV + (j-PADC)];
            st[c] = 2.f*vv*sp*(DTF*DTF);
        }
    }
    gbar(bar, ++bn);

    // time loop: one barrier per step
    float *wcb=wA, *wpb=wB, *sccb=sA, *scpb=sB;
    float *pxc=pxA, *pxn=pxB, *pxsc=pxsA, *pxsn=pxsB;
    float *pyc=pyA, *pyn=pyB, *pysc=pysA, *pysn=pysB;

    for (int t = 0; t < NTS; ++t) {
        for (int c = tid; c < NTOT; c += nth)
            cell_update(c, t, wcb, wpb, sccb, scpb,
                        pxc, pxn, pyc, pyn, pxsc, pxsn, pysc, pysn,
                        zx, zy, zxs, zys, v2, st, axv, bxv, ayv, byv,
                        A.amp, A.sloc);
        gbar(bar, ++bn);

        // gather after barrier: reads just-written scpb; next step only READS
        // that buffer (as sccb), so racing ahead is safe.
        if (tid < NSHOT*NRECV) {
            int s = tid / NRECV, rr = tid - s*NRECV;
            int ri = A.rloc[(s*NRECV+rr)*2+0] + PADC;
            int rj = A.rloc[(s*NRECV+rr)*2+1] + PADC;
            A.out[(s*NRECV+rr)*NTS + t] = scpb[s*NCELL + ri*NYW + rj];
        }

        float* tm;
        tm=wcb;  wcb=wpb;   wpb=tm;
        tm=sccb; sccb=scpb; scpb=tm;
        tm=pxc;  pxc=pxn;   pxn=tm;
        tm=pyc;  pyc=pyn;   pyn=tm;
        tm=pxsc; pxsc=pxsn; pxsn=tm;
        tm=pysc; pysc=pysn; pysn=tm;
    }
}

// ================= fallback multi-kernel path (verified round-2) =================
__global__ void k_vmax(const float* __restrict__ v, unsigned* __restrict__ vmx) {
    __shared__ float sm[256];
    float m = 0.f;
    for (int idx = blockIdx.x*256 + threadIdx.x; idx < NZV*NYV; idx += gridDim.x*256)
        m = fmaxf(m, fabsf(v[idx]));
    sm[threadIdx.x] = m; __syncthreads();
    for (int o = 128; o > 0; o >>= 1) {
        if (threadIdx.x < o) sm[threadIdx.x] = fmaxf(sm[threadIdx.x], sm[threadIdx.x+o]);
        __syncthreads();
    }
    if (threadIdx.x == 0) atomicMax(vmx, __float_as_uint(sm[0]));
}

__global__ void k_prep(const float* __restrict__ v, const float* __restrict__ sc,
                       float* __restrict__ v2dt2, float* __restrict__ sterm) {
    int c = blockIdx.x*blockDim.x + threadIdx.x;
    if (c >= NCELL) return;
    int i = c / NYW, j = c - (c / NYW)*NYW;
    int iz = min(max(i - PADC, 0), NZV-1);
    int iy = min(max(j - PADC, 0), NYV-1);
    float vv = v[iz*NYV + iy];
    v2dt2[c] = vv*vv*(DTF*DTF);
    float sp = 0.f;
    if (i >= PADC && i < PADC+NZV && j >= PADC && j < PADC+NYV)
        sp = sc[(i-PADC)*NYV + (j-PADC)];
    sterm[c] = 2.f*vv*sp*(DTF*DTF);
}

__global__ void k_prof(const unsigned* __restrict__ vmx,
                       float* __restrict__ axv, float* __restrict__ bxv,
                       float* __restrict__ ayv, float* __restrict__ byv) {
    int x = threadIdx.x;
    float vmax = __uint_as_float(vmx[0]);
    if (x < NX)  prof1(x, NX,  5.0f, vmax, &axv[x], &bxv[x]);
    if (x < NYW) prof1(x, NYW, 5.0f, vmax, &ayv[x], &byv[x]);
}

__global__ __launch_bounds__(256) void k_fstep(
    const float* __restrict__ wf,   float* __restrict__ wold,
    const float* __restrict__ wsf,  float* __restrict__ wsold,
    const float* __restrict__ pxo,  float* __restrict__ pxn,
    const float* __restrict__ pyo,  float* __restrict__ pyn,
    const float* __restrict__ pxso, float* __restrict__ pxsn,
    const float* __restrict__ pyso, float* __restrict__ pysn,
    float* __restrict__ zx,  float* __restrict__ zy,
    float* __restrict__ zxs, float* __restrict__ zys,
    const float* __restrict__ v2, const float* __restrict__ st,
    const float* __restrict__ axv, const float* __restrict__ bxv,
    const float* __restrict__ ayv, const float* __restrict__ byv,
    const float* __restrict__ amp, const int* __restrict__ sloc,
    const int* __restrict__ rloc, float* __restrict__ out, int t)
{
    int bid = blockIdx.x;
    if (bid >= NSB) {
        if (t == 0) return;
        int g = (bid - NSB)*256 + threadIdx.x;
        if (g >= NSHOT*NRECV) return;
        int s = g / NRECV, rr = g - s*NRECV;
        int ri = rloc[(s*NRECV+rr)*2+0] + PADC;
        int rj = rloc[(s*NRECV+rr)*2+1] + PADC;
        out[(s*NRECV+rr)*NTS + (t-1)] = wsf[s*NCELL + ri*NYW + rj];
        return;
    }
    int c = bid*256 + threadIdx.x;
    if (c >= NTOT) return;
    cell_update(c, t, wf, wold, wsf, wsold,
                pxo, pxn, pyo, pyn, pxso, pxsn, pyso, pysn,
                zx, zy, zxs, zys, v2, st, axv, bxv, ayv, byv, amp, sloc);
}

__global__ void k_gtail(const float* __restrict__ wsn, const int* __restrict__ rloc,
                        float* __restrict__ out) {
    int g = blockIdx.x*blockDim.x + threadIdx.x;
    if (g >= NSHOT*NRECV) return;
    int s = g / NRECV, rr = g - s*NRECV;
    int ri = rloc[(s*NRECV+rr)*2+0] + PADC;
    int rj = rloc[(s*NRECV+rr)*2+1] + PADC;
    out[(s*NRECV+rr)*NTS + (NTS-1)] = wsn[s*NCELL + ri*NYW + rj];
}

extern "C" void kernel_launch(void* const* d_in, const int* in_sizes, int n_in,
                              void* d_out, int out_size, void* d_ws, size_t ws_size,
                              hipStream_t stream) {
    const float* v    = (const float*)d_in[0];
    const float* scat = (const float*)d_in[1];
    const float* amp  = (const float*)d_in[2];
    const int*   sloc = (const int*)d_in[3];
    const int*   rloc = (const int*)d_in[4];
    float* out = (float*)d_out;
    float* ws  = (float*)d_ws;

    SimArgs args;
    args.v = v; args.scat = scat; args.amp = amp;
    args.sloc = sloc; args.rloc = rloc;
    args.out = out; args.ws = ws;

    // zero barrier counters + gen + vmax accumulator (first 4 KB)
    hipMemsetAsync(ws, 0, BARF*sizeof(float), stream);

    void* kargs[] = { &args };
    hipError_t e = hipLaunchCooperativeKernel((const void*)k_sim, dim3(NBLK), dim3(NTHR),
                                              kargs, 0, stream);
    if (e == hipSuccess) return;

    // ---- fallback: verified multi-kernel path
    float* base = ws + BARF;
    const size_t F = (size_t)NTOT;
    float* wA   = base;
    float* wB   = wA + F;
    float* sA   = wB + F;
    float* sB   = sA + F;
    float* pxA  = sB + F;
    float* pxB  = pxA + PXSZ;
    float* pxsA = pxB + PXSZ;
    float* pxsB = pxsA + PXSZ;
    float* zx   = pxsB + PXSZ;
    float* zxs  = zx + PXSZ;
    float* pyA  = zxs + PXSZ;
    float* pyB  = pyA + PYSZ;
    float* pysA = pyB + PYSZ;
    float* pysB = pysA + PYSZ;
    float* zy   = pysB + PYSZ;
    float* zys  = zy + PYSZ;
    float* v2   = zys + PYSZ;
    float* st   = v2 + NCELL;
    float* axv  = st + NCELL;
    float* bxv  = axv + NX;
    float* ayv  = bxv + NX;
    float* byv  = ayv + NYW;
    unsigned* vmx = (unsigned*)ws + 544;

    size_t zero_floats = 4*F + 6*(size_t)PXSZ + 6*(size_t)PYSZ;
    hipMemsetAsync(base, 0, zero_floats*sizeof(float), stream);

    hipLaunchKernelGGL(k_vmax, dim3(64), dim3(256), 0, stream, v, vmx);
    hipLaunchKernelGGL(k_prep, dim3((NCELL+255)/256), dim3(256), 0, stream, v, scat, v2, st);
    hipLaunchKernelGGL(k_prof, dim3(1), dim3(512), 0, stream, vmx, axv, bxv, ayv, byv);

    float* wc  = wA;  float* wp  = wB;
    float* scc = sA;  float* scp = sB;
    float* pxc = pxA; float* pxn = pxB;
    float* pyc = pyA; float* pyn = pyB;
    float* pxsc = pxsA; float* pxsn = pxsB;
    float* pysc = pysA; float* pysn = pysB;

    for (int t = 0; t < NTS; ++t) {
        hipLaunchKernelGGL(k_fstep, dim3(NSB + GB), dim3(256), 0, stream,
                           wc, wp, scc, scp,
                           pxc, pxn, pyc, pyn, pxsc, pxsn, pysc, pysn,
                           zx, zy, zxs, zys,
                           v2, st, axv, bxv, ayv, byv,
                           amp, sloc, rloc, out, t);
        float* tmp;
        tmp = wc;  wc  = wp;  wp  = tmp;
        tmp = scc; scc = scp; scp = tmp;
        tmp = pxc; pxc = pxn; pxn = tmp;
        tmp = pyc; pyc = pyn; pyn = tmp;
        tmp = pxsc; pxsc = pxsn; pxsn = tmp;
        tmp = pysc; pysc = pysn; pysn = tmp;
    }
    hipLaunchKernelGGL(k_gtail, dim3(2), dim3(256), 0, stream, scc, rloc, out);
}

// Round 6
// 1754.327 us; speedup vs baseline: 3.1875x; 1.5622x over previous
//
#include <hip/hip_runtime.h>

#define DTF   0.001f
#define NZV   250
#define NYV   350
#define NX    294          // 250 + 44
#define NYW   394          // 350 + 44
#define PADC  22
#define NSHOT 4
#define NTS   48
#define NRECV 100
#define NCELL (NX*NYW)     // 115836
#define NTOT  (NSHOT*NCELL)
#define XBL   22           // x in [0,21] is low band
#define XBH   (NX-22)      // 272: x >= 272 is high band
#define YBH   (NYW-22)     // 372
#define NB    44
#define PXSZ  (NSHOT*NB*NYW)   // x-band state: [shot][44][NYW]
#define PYSZ  (NSHOT*NX*NB)    // y-band state: [shot][NX][44]
#define NSB   ((NTOT+255)/256) // fallback stencil blocks
#define GB    2                // fallback gather blocks
#define NTHR  256
#define NBLK  512
#define SBLK  128              // blocks per shot partition
#define BARF  32768            // floats reserved at ws head for barrier+vmx

// barrier layout (uint offsets into ws)
#define GFLG  0                // global flags: 512 x 16 uints
#define GGEN  8192             // global gen line
#define VMXO  8208             // vmax accumulator
#define SFLG  8224             // shot flags: 4 x (128 x 16)
#define SSTR  2048
#define SGEN  16416            // shot gen lines: 4 x 16

__device__ __forceinline__ int xbi(int i) {
    return ((unsigned)i < XBL) ? i : ((i >= XBH && i < NX) ? i-(NX-NB) : -1);
}
__device__ __forceinline__ int ybi(int j) {
    return ((unsigned)j < XBL) ? j : ((j >= YBH && j < NYW) ? j-(NYW-NB) : -1);
}
__device__ __forceinline__ float ldz(const float* __restrict__ w, int i, int j) {
    return ((unsigned)i < (unsigned)NX && (unsigned)j < (unsigned)NYW) ? w[i*NYW + j] : 0.f;
}
__device__ __forceinline__ float d1x(const float* __restrict__ w, int i, int j) {
    return (8.f*(ldz(w,i+1,j) - ldz(w,i-1,j)) - (ldz(w,i+2,j) - ldz(w,i-2,j))) * (1.f/60.f);
}
__device__ __forceinline__ float d1y(const float* __restrict__ w, int i, int j) {
    return (8.f*(ldz(w,i,j+1) - ldz(w,i,j-1)) - (ldz(w,i,j+2) - ldz(w,i,j-2))) * (1.f/60.f);
}
__device__ __forceinline__ float d2x(const float* __restrict__ w, int i, int j, float cc) {
    return (-(ldz(w,i+2,j)+ldz(w,i-2,j)) + 16.f*(ldz(w,i+1,j)+ldz(w,i-1,j)) - 30.f*cc) * (1.f/300.f);
}
__device__ __forceinline__ float d2y(const float* __restrict__ w, int i, int j, float cc) {
    return (-(ldz(w,i,j+2)+ldz(w,i,j-2)) + 16.f*(ldz(w,i,j+1)+ldz(w,i,j-1)) - 30.f*cc) * (1.f/300.f);
}
__device__ __forceinline__ void prof1(int x, int n, float d, float vmax, float* a, float* b) {
    float fl = fminf(fmaxf((float)(2 + 20 - x)/20.f, 0.f), 1.f);
    float fh = fminf(fmaxf((float)(x - (n - 23))/20.f, 0.f), 1.f);
    float fr = fmaxf(fl, fh);
    float sigma = 3.f*vmax*logf(1000.f)/(2.f*20.f*d)*fr*fr;
    float alpha = 3.14159265358979f*25.f*(1.f - fr);
    float bb = expf(-(sigma+alpha)*DTF);
    *a = sigma/(sigma+alpha+1e-9f)*(bb-1.f);
    *b = bb;
}

// Fused per-cell update (verified rounds 2/4/5).
__device__ __forceinline__ void cell_update(
    int c, int t,
    const float* __restrict__ wcb, float* __restrict__ wpb,
    const float* __restrict__ sccb, float* __restrict__ scpb,
    const float* __restrict__ pxc, float* __restrict__ pxn,
    const float* __restrict__ pyc, float* __restrict__ pyn,
    const float* __restrict__ pxsc, float* __restrict__ pxsn,
    const float* __restrict__ pysc, float* __restrict__ pysn,
    float* __restrict__ zx, float* __restrict__ zy,
    float* __restrict__ zxs, float* __restrict__ zys,
    const float* __restrict__ v2, const float* __restrict__ st,
    const float* __restrict__ axv, const float* __restrict__ bxv,
    const float* __restrict__ ayv, const float* __restrict__ byv,
    const float* __restrict__ amp, const int* __restrict__ sloc)
{
    int s = c / NCELL; int r = c - s*NCELL;
    int i = r / NYW;   int j = r - i*NYW;
    const float* w  = wcb  + s*NCELL;
    const float* ww = sccb + s*NCELL;

    float wcv  = w[r];
    float wscv = ww[r];

    float tx  = d2x(w,  i, j, wcv);
    float txs = d2x(ww, i, j, wscv);
    float ty  = d2y(w,  i, j, wcv);
    float tys = d2y(ww, i, j, wscv);

    int ib = xbi(i);
    int jb = ybi(j);

    if (i <= XBL+1 || i >= XBH-2) {
        float pv[5], pvs[5];
        #pragma unroll
        for (int k = 0; k < 5; ++k) {
            int ik = i + k - 2; int b = xbi(ik);
            float p = 0.f, ps = 0.f;
            if (b >= 0) {
                float bxk = bxv[ik], axk = axv[ik];
                int o = (s*NB + b)*NYW + j;
                p  = bxk*pxc[o]  + axk*d1x(w,  ik, j);
                ps = bxk*pxsc[o] + axk*d1x(ww, ik, j);
            }
            pv[k] = p; pvs[k] = ps;
        }
        tx  += (8.f*(pv[3]-pv[1])  - (pv[4]-pv[0]))  * (1.f/60.f);
        txs += (8.f*(pvs[3]-pvs[1]) - (pvs[4]-pvs[0])) * (1.f/60.f);
        if (ib >= 0) {
            int o = (s*NB + ib)*NYW + j;
            pxn[o] = pv[2]; pxsn[o] = pvs[2];
        }
    }

    if (j <= XBL+1 || j >= YBH-2) {
        float pv[5], pvs[5];
        #pragma unroll
        for (int k = 0; k < 5; ++k) {
            int jk = j + k - 2; int b = ybi(jk);
            float p = 0.f, ps = 0.f;
            if (b >= 0) {
                float byk = byv[jk], ayk = ayv[jk];
                int o = (s*NX + i)*NB + b;
                p  = byk*pyc[o]  + ayk*d1y(w,  i, jk);
                ps = byk*pysc[o] + ayk*d1y(ww, i, jk);
            }
            pv[k] = p; pvs[k] = ps;
        }
        ty  += (8.f*(pv[3]-pv[1])  - (pv[4]-pv[0]))  * (1.f/60.f);
        tys += (8.f*(pvs[3]-pvs[1]) - (pvs[4]-pvs[0])) * (1.f/60.f);
        if (jb >= 0) {
            int o = (s*NX + i)*NB + jb;
            pyn[o] = pv[2]; pysn[o] = pvs[2];
        }
    }

    float zxv = 0.f, zyv = 0.f, zxsv = 0.f, zysv = 0.f;
    if (ib >= 0) {
        int o = (s*NB + ib)*NYW + j;
        float bx = bxv[i], ax = axv[i];
        zxv  = bx*zx[o]  + ax*tx;  zx[o]  = zxv;
        zxsv = bx*zxs[o] + ax*txs; zxs[o] = zxsv;
    }
    if (jb >= 0) {
        int o = (s*NX + i)*NB + jb;
        float by = byv[j], ay = ayv[j];
        zyv  = by*zy[o]  + ay*ty;  zy[o]  = zyv;
        zysv = by*zys[o] + ay*tys; zys[o] = zysv;
    }

    float lap  = tx + zxv + ty + zyv;
    float laps = txs + zxsv + tys + zysv;
    float vd   = v2[r];
    float wn   = vd*lap + 2.f*wcv - wpb[c];
    if (i == sloc[s*2] + PADC && j == sloc[s*2+1] + PADC)
        wn += vd * amp[s*NTS + t];
    float wsn = vd*laps + 2.f*wscv - scpb[c] + st[r]*lap;
    wpb[c]  = wn;
    scpb[c] = wsn;
}

// ---- flag-based barrier: per-block release-stores + poller scan ----
// flags at bar[flg_off + b*16], gen at bar[gen_off]. lb==0 is the poller.
__device__ __forceinline__ void fbar(unsigned* bar, int flg_off, int gen_off,
                                     int lb, int nblk, unsigned target) {
    __syncthreads();
    if (lb == 0) {
        for (int b = threadIdx.x; b < nblk; b += NTHR) {
            if (b != 0) {
                while (__hip_atomic_load(&bar[flg_off + b*16], __ATOMIC_RELAXED,
                                         __HIP_MEMORY_SCOPE_AGENT) < target)
                    __builtin_amdgcn_s_sleep(1);
            }
        }
        __builtin_amdgcn_fence(__ATOMIC_ACQUIRE, "agent");
        __syncthreads();
        if (threadIdx.x == 0)
            __hip_atomic_store(&bar[gen_off], target, __ATOMIC_RELEASE,
                               __HIP_MEMORY_SCOPE_AGENT);
    } else {
        if (threadIdx.x == 0) {
            __hip_atomic_store(&bar[flg_off + lb*16], target, __ATOMIC_RELEASE,
                               __HIP_MEMORY_SCOPE_AGENT);
            while (__hip_atomic_load(&bar[gen_off], __ATOMIC_RELAXED,
                                     __HIP_MEMORY_SCOPE_AGENT) < target)
                __builtin_amdgcn_s_sleep(2);
            __builtin_amdgcn_fence(__ATOMIC_ACQUIRE, "agent");
        }
        __syncthreads();
    }
}

struct SimArgs {
    const float* v; const float* scat; const float* amp;
    const int* sloc; const int* rloc;
    float* out; float* ws;
};

// ================= persistent single-kernel path =================
__global__ __launch_bounds__(NTHR, 2) void k_sim(SimArgs A) {
    const int tid = blockIdx.x*NTHR + threadIdx.x;
    const int nth = NBLK*NTHR;
    const int s   = blockIdx.x / SBLK;          // shot partition
    const int lb  = blockIdx.x - s*SBLK;        // local block in partition
    const int lt  = lb*NTHR + threadIdx.x;      // local thread in partition
    const int lnt = SBLK*NTHR;

    unsigned* bar = (unsigned*)A.ws;
    unsigned* vmx = bar + VMXO;

    float* base = A.ws + BARF;
    const size_t F = (size_t)NTOT;
    float* wA   = base;
    float* wB   = wA + F;
    float* sA   = wB + F;
    float* sB   = sA + F;
    float* pxA  = sB + F;
    float* pxB  = pxA + PXSZ;
    float* pxsA = pxB + PXSZ;
    float* pxsB = pxsA + PXSZ;
    float* zx   = pxsB + PXSZ;
    float* zxs  = zx + PXSZ;
    float* pyA  = zxs + PXSZ;
    float* pyB  = pyA + PYSZ;
    float* pysA = pyB + PYSZ;
    float* pysB = pysA + PYSZ;
    float* zy   = pysB + PYSZ;
    float* zys  = zy + PYSZ;
    float* v2   = zys + PYSZ;
    float* st   = v2 + NCELL;
    float* axv  = st + NCELL;
    float* bxv  = axv + NX;
    float* ayv  = bxv + NX;
    float* byv  = ayv + NYW;

    // phase 0: zero recurrence state (barrier region zeroed by host memset)
    const size_t ZTOT = 4*F + 6*(size_t)PXSZ + 6*(size_t)PYSZ;
    for (size_t z = (size_t)tid; z < ZTOT; z += (size_t)nth) base[z] = 0.f;
    fbar(bar, GFLG, GGEN, blockIdx.x, NBLK, 1u);

    // phase 1: vmax
    {
        float m = 0.f;
        for (int idx = tid; idx < NZV*NYV; idx += nth) m = fmaxf(m, fabsf(A.v[idx]));
        __shared__ float sm[NTHR];
        sm[threadIdx.x] = m; __syncthreads();
        for (int o = NTHR/2; o > 0; o >>= 1) {
            if (threadIdx.x < o) sm[threadIdx.x] = fmaxf(sm[threadIdx.x], sm[threadIdx.x+o]);
            __syncthreads();
        }
        if (threadIdx.x == 0) atomicMax(vmx, __float_as_uint(sm[0]));
    }
    fbar(bar, GFLG, GGEN, blockIdx.x, NBLK, 2u);

    // phase 2: PML profiles + v2dt2/sterm
    {
        float vmax = __uint_as_float(__hip_atomic_load(vmx, __ATOMIC_RELAXED,
                                                       __HIP_MEMORY_SCOPE_AGENT));
        if (tid < NX) prof1(tid, NX, 5.0f, vmax, &axv[tid], &bxv[tid]);
        else if (tid < NX + NYW) { int y = tid - NX; prof1(y, NYW, 5.0f, vmax, &ayv[y], &byv[y]); }
        for (int c = tid; c < NCELL; c += nth) {
            int i = c / NYW, j = c - (c / NYW)*NYW;
            int iz = min(max(i - PADC, 0), NZV-1);
            int iy = min(max(j - PADC, 0), NYV-1);
            float vv = A.v[iz*NYV + iy];
            v2[c] = vv*vv*(DTF*DTF);
            float sp = 0.f;
            if (i >= PADC && i < PADC+NZV && j >= PADC && j < PADC+NYV)
                sp = A.scat[(i-PADC)*NYV + (j-PADC)];
            st[c] = 2.f*vv*sp*(DTF*DTF);
        }
    }
    fbar(bar, GFLG, GGEN, blockIdx.x, NBLK, 3u);

    // time loop: per-shot barriers (shots are independent)
    float *wcb=wA, *wpb=wB, *sccb=sA, *scpb=sB;
    float *pxc=pxA, *pxn=pxB, *pxsc=pxsA, *pxsn=pxsB;
    float *pyc=pyA, *pyn=pyB, *pysc=pysA, *pysn=pysB;

    const int sflg = SFLG + s*SSTR;
    const int sgen = SGEN + s*16;

    for (int t = 0; t < NTS; ++t) {
        for (int r = lt; r < NCELL; r += lnt)
            cell_update(s*NCELL + r, t, wcb, wpb, sccb, scpb,
                        pxc, pxn, pyc, pyn, pxsc, pxsn, pysc, pysn,
                        zx, zy, zxs, zys, v2, st, axv, bxv, ayv, byv,
                        A.amp, A.sloc);
        fbar(bar, sflg, sgen, lb, SBLK, (unsigned)(t+1));

        // gather: reads just-written scpb; next step only READS that buffer.
        if (lt < NRECV) {
            int ri = A.rloc[(s*NRECV+lt)*2+0] + PADC;
            int rj = A.rloc[(s*NRECV+lt)*2+1] + PADC;
            A.out[(s*NRECV+lt)*NTS + t] = scpb[s*NCELL + ri*NYW + rj];
        }

        float* tm;
        tm=wcb;  wcb=wpb;   wpb=tm;
        tm=sccb; sccb=scpb; scpb=tm;
        tm=pxc;  pxc=pxn;   pxn=tm;
        tm=pyc;  pyc=pyn;   pyn=tm;
        tm=pxsc; pxsc=pxsn; pxsn=tm;
        tm=pysc; pysc=pysn; pysn=tm;
    }
}

// ================= fallback multi-kernel path (verified round-2) =================
__global__ void k_vmax(const float* __restrict__ v, unsigned* __restrict__ vmx) {
    __shared__ float sm[256];
    float m = 0.f;
    for (int idx = blockIdx.x*256 + threadIdx.x; idx < NZV*NYV; idx += gridDim.x*256)
        m = fmaxf(m, fabsf(v[idx]));
    sm[threadIdx.x] = m; __syncthreads();
    for (int o = 128; o > 0; o >>= 1) {
        if (threadIdx.x < o) sm[threadIdx.x] = fmaxf(sm[threadIdx.x], sm[threadIdx.x+o]);
        __syncthreads();
    }
    if (threadIdx.x == 0) atomicMax(vmx, __float_as_uint(sm[0]));
}

__global__ void k_prep(const float* __restrict__ v, const float* __restrict__ sc,
                       float* __restrict__ v2dt2, float* __restrict__ sterm) {
    int c = blockIdx.x*blockDim.x + threadIdx.x;
    if (c >= NCELL) return;
    int i = c / NYW, j = c - (c / NYW)*NYW;
    int iz = min(max(i - PADC, 0), NZV-1);
    int iy = min(max(j - PADC, 0), NYV-1);
    float vv = v[iz*NYV + iy];
    v2dt2[c] = vv*vv*(DTF*DTF);
    float sp = 0.f;
    if (i >= PADC && i < PADC+NZV && j >= PADC && j < PADC+NYV)
        sp = sc[(i-PADC)*NYV + (j-PADC)];
    sterm[c] = 2.f*vv*sp*(DTF*DTF);
}

__global__ void k_prof(const unsigned* __restrict__ vmx,
                       float* __restrict__ axv, float* __restrict__ bxv,
                       float* __restrict__ ayv, float* __restrict__ byv) {
    int x = threadIdx.x;
    float vmax = __uint_as_float(vmx[0]);
    if (x < NX)  prof1(x, NX,  5.0f, vmax, &axv[x], &bxv[x]);
    if (x < NYW) prof1(x, NYW, 5.0f, vmax, &ayv[x], &byv[x]);
}

__global__ __launch_bounds__(256) void k_fstep(
    const float* __restrict__ wf,   float* __restrict__ wold,
    const float* __restrict__ wsf,  float* __restrict__ wsold,
    const float* __restrict__ pxo,  float* __restrict__ pxn,
    const float* __restrict__ pyo,  float* __restrict__ pyn,
    const float* __restrict__ pxso, float* __restrict__ pxsn,
    const float* __restrict__ pyso, float* __restrict__ pysn,
    float* __restrict__ zx,  float* __restrict__ zy,
    float* __restrict__ zxs, float* __restrict__ zys,
    const float* __restrict__ v2, const float* __restrict__ st,
    const float* __restrict__ axv, const float* __restrict__ bxv,
    const float* __restrict__ ayv, const float* __restrict__ byv,
    const float* __restrict__ amp, const int* __restrict__ sloc,
    const int* __restrict__ rloc, float* __restrict__ out, int t)
{
    int bid = blockIdx.x;
    if (bid >= NSB) {
        if (t == 0) return;
        int g = (bid - NSB)*256 + threadIdx.x;
        if (g >= NSHOT*NRECV) return;
        int s = g / NRECV, rr = g - s*NRECV;
        int ri = rloc[(s*NRECV+rr)*2+0] + PADC;
        int rj = rloc[(s*NRECV+rr)*2+1] + PADC;
        out[(s*NRECV+rr)*NTS + (t-1)] = wsf[s*NCELL + ri*NYW + rj];
        return;
    }
    int c = bid*256 + threadIdx.x;
    if (c >= NTOT) return;
    cell_update(c, t, wf, wold, wsf, wsold,
                pxo, pxn, pyo, pyn, pxso, pxsn, pyso, pysn,
                zx, zy, zxs, zys, v2, st, axv, bxv, ayv, byv, amp, sloc);
}

__global__ void k_gtail(const float* __restrict__ wsn, const int* __restrict__ rloc,
                        float* __restrict__ out) {
    int g = blockIdx.x*blockDim.x + threadIdx.x;
    if (g >= NSHOT*NRECV) return;
    int s = g / NRECV, rr = g - s*NRECV;
    int ri = rloc[(s*NRECV+rr)*2+0] + PADC;
    int rj = rloc[(s*NRECV+rr)*2+1] + PADC;
    out[(s*NRECV+rr)*NTS + (NTS-1)] = wsn[s*NCELL + ri*NYW + rj];
}

extern "C" void kernel_launch(void* const* d_in, const int* in_sizes, int n_in,
                              void* d_out, int out_size, void* d_ws, size_t ws_size,
                              hipStream_t stream) {
    const float* v    = (const float*)d_in[0];
    const float* scat = (const float*)d_in[1];
    const float* amp  = (const float*)d_in[2];
    const int*   sloc = (const int*)d_in[3];
    const int*   rloc = (const int*)d_in[4];
    float* out = (float*)d_out;
    float* ws  = (float*)d_ws;

    SimArgs args;
    args.v = v; args.scat = scat; args.amp = amp;
    args.sloc = sloc; args.rloc = rloc;
    args.out = out; args.ws = ws;

    // zero barrier flags + gens + vmax accumulator
    hipMemsetAsync(ws, 0, BARF*sizeof(float), stream);

    void* kargs[] = { &args };
    hipError_t e = hipLaunchCooperativeKernel((const void*)k_sim, dim3(NBLK), dim3(NTHR),
                                              kargs, 0, stream);
    if (e == hipSuccess) return;

    // ---- fallback: verified multi-kernel path
    float* base = ws + BARF;
    const size_t F = (size_t)NTOT;
    float* wA   = base;
    float* wB   = wA + F;
    float* sA   = wB + F;
    float* sB   = sA + F;
    float* pxA  = sB + F;
    float* pxB  = pxA + PXSZ;
    float* pxsA = pxB + PXSZ;
    float* pxsB = pxsA + PXSZ;
    float* zx   = pxsB + PXSZ;
    float* zxs  = zx + PXSZ;
    float* pyA  = zxs + PXSZ;
    float* pyB  = pyA + PYSZ;
    float* pysA = pyB + PYSZ;
    float* pysB = pysA + PYSZ;
    float* zy   = pysB + PYSZ;
    float* zys  = zy + PYSZ;
    float* v2   = zys + PYSZ;
    float* st   = v2 + NCELL;
    float* axv  = st + NCELL;
    float* bxv  = axv + NX;
    float* ayv  = bxv + NX;
    float* byv  = ayv + NYW;
    unsigned* vmx = (unsigned*)ws + VMXO;

    size_t zero_floats = 4*F + 6*(size_t)PXSZ + 6*(size_t)PYSZ;
    hipMemsetAsync(base, 0, zero_floats*sizeof(float), stream);

    hipLaunchKernelGGL(k_vmax, dim3(64), dim3(256), 0, stream, v, vmx);
    hipLaunchKernelGGL(k_prep, dim3((NCELL+255)/256), dim3(256), 0, stream, v, scat, v2, st);
    hipLaunchKernelGGL(k_prof, dim3(1), dim3(512), 0, stream, vmx, axv, bxv, ayv, byv);

    float* wc  = wA;  float* wp  = wB;
    float* scc = sA;  float* scp = sB;
    float* pxc = pxA; float* pxn = pxB;
    float* pyc = pyA; float* pyn = pyB;
    float* pxsc = pxsA; float* pxsn = pxsB;
    float* pysc = pysA; float* pysn = pysB;

    for (int t = 0; t < NTS; ++t) {
        hipLaunchKernelGGL(k_fstep, dim3(NSB + GB), dim3(256), 0, stream,
                           wc, wp, scc, scp,
                           pxc, pxn, pyc, pyn, pxsc, pxsn, pysc, pysn,
                           zx, zy, zxs, zys,
                           v2, st, axv, bxv, ayv, byv,
                           amp, sloc, rloc, out, t);
        float* tmp;
        tmp = wc;  wc  = wp;  wp  = tmp;
        tmp = scc; scc = scp; scp = tmp;
        tmp = pxc; pxc = pxn; pxn = tmp;
        tmp = pyc; pyc = pyn; pyn = tmp;
        tmp = pxsc; pxsc = pxsn; pxsn = tmp;
        tmp = pysc; pysc = pysn; pysn = tmp;
    }
    hipLaunchKernelGGL(k_gtail, dim3(2), dim3(256), 0, stream, scc, rloc, out);
}

// Round 7
// 1624.974 us; speedup vs baseline: 3.4413x; 1.0796x over previous
//
#include <hip/hip_runtime.h>

#define DTF   0.001f
#define NZV   250
#define NYV   350
#define NX    294          // 250 + 44
#define NYW   394          // 350 + 44
#define PADC  22
#define NSHOT 4
#define NTS   48
#define NRECV 100
#define NCELL (NX*NYW)     // 115836
#define NTOT  (NSHOT*NCELL)
#define XBL   22           // x in [0,21] is low band
#define XBH   (NX-22)      // 272: x >= 272 is high band
#define YBH   (NYW-22)     // 372
#define NB    44
#define PXSZ  (NSHOT*NB*NYW)   // x-band state: [shot][44][NYW]
#define PYSZ  (NSHOT*NX*NB)    // y-band state: [shot][NX][44]
#define NSB   ((NTOT+255)/256) // fallback stencil blocks
#define GB    2                // fallback gather blocks
#define NTHR  256
#define NBLK  512
#define SBLK  128              // blocks per shot partition
#define BARF  32768            // floats reserved at ws head for barrier+vmx

// barrier layout (uint offsets into ws)
#define GFLG  0                // global flags: 512 x 16 uints
#define GGEN  8192             // global gen line
#define VMXO  8208             // vmax accumulator
#define SFLG  8224             // shot flags: 4 x (128 x 16)
#define SSTR  2048
#define SGEN  16416            // shot gen lines: 4 x 16

// L3-routed accesses for mutable state (bypass per-XCD L2; coherence point
// is the fabric/L3 — proven by r5/r6 relaxed-flag visibility across XCDs).
__device__ __forceinline__ float ld3(const float* p) {
    return __hip_atomic_load(const_cast<float*>(p), __ATOMIC_RELAXED,
                             __HIP_MEMORY_SCOPE_AGENT);
}
__device__ __forceinline__ void st3(float* p, float v) {
    __hip_atomic_store(p, v, __ATOMIC_RELAXED, __HIP_MEMORY_SCOPE_AGENT);
}

__device__ __forceinline__ int xbi(int i) {
    return ((unsigned)i < XBL) ? i : ((i >= XBH && i < NX) ? i-(NX-NB) : -1);
}
__device__ __forceinline__ int ybi(int j) {
    return ((unsigned)j < XBL) ? j : ((j >= YBH && j < NYW) ? j-(NYW-NB) : -1);
}
__device__ __forceinline__ float ldz(const float* __restrict__ w, int i, int j) {
    return ((unsigned)i < (unsigned)NX && (unsigned)j < (unsigned)NYW) ? ld3(&w[i*NYW + j]) : 0.f;
}
__device__ __forceinline__ float d1x(const float* __restrict__ w, int i, int j) {
    return (8.f*(ldz(w,i+1,j) - ldz(w,i-1,j)) - (ldz(w,i+2,j) - ldz(w,i-2,j))) * (1.f/60.f);
}
__device__ __forceinline__ float d1y(const float* __restrict__ w, int i, int j) {
    return (8.f*(ldz(w,i,j+1) - ldz(w,i,j-1)) - (ldz(w,i,j+2) - ldz(w,i,j-2))) * (1.f/60.f);
}
__device__ __forceinline__ float d2x(const float* __restrict__ w, int i, int j, float cc) {
    return (-(ldz(w,i+2,j)+ldz(w,i-2,j)) + 16.f*(ldz(w,i+1,j)+ldz(w,i-1,j)) - 30.f*cc) * (1.f/300.f);
}
__device__ __forceinline__ float d2y(const float* __restrict__ w, int i, int j, float cc) {
    return (-(ldz(w,i,j+2)+ldz(w,i,j-2)) + 16.f*(ldz(w,i,j+1)+ldz(w,i,j-1)) - 30.f*cc) * (1.f/300.f);
}
__device__ __forceinline__ void prof1(int x, int n, float d, float vmax, float* a, float* b) {
    float fl = fminf(fmaxf((float)(2 + 20 - x)/20.f, 0.f), 1.f);
    float fh = fminf(fmaxf((float)(x - (n - 23))/20.f, 0.f), 1.f);
    float fr = fmaxf(fl, fh);
    float sigma = 3.f*vmax*logf(1000.f)/(2.f*20.f*d)*fr*fr;
    float alpha = 3.14159265358979f*25.f*(1.f - fr);
    float bb = expf(-(sigma+alpha)*DTF);
    *a = sigma/(sigma+alpha+1e-9f)*(bb-1.f);
    *b = bb;
}

// Fused per-cell update (verified rounds 2/4/5/6). Mutable state via ld3/st3.
__device__ __forceinline__ void cell_update(
    int c, int t,
    const float* __restrict__ wcb, float* __restrict__ wpb,
    const float* __restrict__ sccb, float* __restrict__ scpb,
    const float* __restrict__ pxc, float* __restrict__ pxn,
    const float* __restrict__ pyc, float* __restrict__ pyn,
    const float* __restrict__ pxsc, float* __restrict__ pxsn,
    const float* __restrict__ pysc, float* __restrict__ pysn,
    float* __restrict__ zx, float* __restrict__ zy,
    float* __restrict__ zxs, float* __restrict__ zys,
    const float* __restrict__ v2, const float* __restrict__ st,
    const float* __restrict__ axv, const float* __restrict__ bxv,
    const float* __restrict__ ayv, const float* __restrict__ byv,
    const float* __restrict__ amp, const int* __restrict__ sloc)
{
    int s = c / NCELL; int r = c - s*NCELL;
    int i = r / NYW;   int j = r - i*NYW;
    const float* w  = wcb  + s*NCELL;
    const float* ww = sccb + s*NCELL;

    float wcv  = ld3(&w[r]);
    float wscv = ld3(&ww[r]);

    float tx  = d2x(w,  i, j, wcv);
    float txs = d2x(ww, i, j, wscv);
    float ty  = d2y(w,  i, j, wcv);
    float tys = d2y(ww, i, j, wscv);

    int ib = xbi(i);
    int jb = ybi(j);

    if (i <= XBL+1 || i >= XBH-2) {
        float pv[5], pvs[5];
        #pragma unroll
        for (int k = 0; k < 5; ++k) {
            int ik = i + k - 2; int b = xbi(ik);
            float p = 0.f, ps = 0.f;
            if (b >= 0) {
                float bxk = bxv[ik], axk = axv[ik];
                int o = (s*NB + b)*NYW + j;
                p  = bxk*ld3(&pxc[o])  + axk*d1x(w,  ik, j);
                ps = bxk*ld3(&pxsc[o]) + axk*d1x(ww, ik, j);
            }
            pv[k] = p; pvs[k] = ps;
        }
        tx  += (8.f*(pv[3]-pv[1])  - (pv[4]-pv[0]))  * (1.f/60.f);
        txs += (8.f*(pvs[3]-pvs[1]) - (pvs[4]-pvs[0])) * (1.f/60.f);
        if (ib >= 0) {
            int o = (s*NB + ib)*NYW + j;
            st3(&pxn[o], pv[2]); st3(&pxsn[o], pvs[2]);
        }
    }

    if (j <= XBL+1 || j >= YBH-2) {
        float pv[5], pvs[5];
        #pragma unroll
        for (int k = 0; k < 5; ++k) {
            int jk = j + k - 2; int b = ybi(jk);
            float p = 0.f, ps = 0.f;
            if (b >= 0) {
                float byk = byv[jk], ayk = ayv[jk];
                int o = (s*NX + i)*NB + b;
                p  = byk*ld3(&pyc[o])  + ayk*d1y(w,  i, jk);
                ps = byk*ld3(&pysc[o]) + ayk*d1y(ww, i, jk);
            }
            pv[k] = p; pvs[k] = ps;
        }
        ty  += (8.f*(pv[3]-pv[1])  - (pv[4]-pv[0]))  * (1.f/60.f);
        tys += (8.f*(pvs[3]-pvs[1]) - (pvs[4]-pvs[0])) * (1.f/60.f);
        if (jb >= 0) {
            int o = (s*NX + i)*NB + jb;
            st3(&pyn[o], pv[2]); st3(&pysn[o], pvs[2]);
        }
    }

    float zxv = 0.f, zyv = 0.f, zxsv = 0.f, zysv = 0.f;
    if (ib >= 0) {
        int o = (s*NB + ib)*NYW + j;
        float bx = bxv[i], ax = axv[i];
        zxv  = bx*ld3(&zx[o])  + ax*tx;  st3(&zx[o],  zxv);
        zxsv = bx*ld3(&zxs[o]) + ax*txs; st3(&zxs[o], zxsv);
    }
    if (jb >= 0) {
        int o = (s*NX + i)*NB + jb;
        float by = byv[j], ay = ayv[j];
        zyv  = by*ld3(&zy[o])  + ay*ty;  st3(&zy[o],  zyv);
        zysv = by*ld3(&zys[o]) + ay*tys; st3(&zys[o], zysv);
    }

    float lap  = tx + zxv + ty + zyv;
    float laps = txs + zxsv + tys + zysv;
    float vd   = v2[r];
    float wn   = vd*lap + 2.f*wcv - ld3(&wpb[c]);
    if (i == sloc[s*2] + PADC && j == sloc[s*2+1] + PADC)
        wn += vd * amp[s*NTS + t];
    float wsn = vd*laps + 2.f*wscv - ld3(&scpb[c]) + st[r]*lap;
    st3(&wpb[c],  wn);
    st3(&scpb[c], wsn);
}

// ---- flag-based barrier: per-block release-stores + poller scan ----
__device__ __forceinline__ void fbar(unsigned* bar, int flg_off, int gen_off,
                                     int lb, int nblk, unsigned target) {
    __syncthreads();
    if (lb == 0) {
        for (int b = threadIdx.x; b < nblk; b += NTHR) {
            if (b != 0) {
                while (__hip_atomic_load(&bar[flg_off + b*16], __ATOMIC_RELAXED,
                                         __HIP_MEMORY_SCOPE_AGENT) < target)
                    __builtin_amdgcn_s_sleep(1);
            }
        }
        __builtin_amdgcn_fence(__ATOMIC_ACQUIRE, "agent");
        __syncthreads();
        if (threadIdx.x == 0)
            __hip_atomic_store(&bar[gen_off], target, __ATOMIC_RELEASE,
                               __HIP_MEMORY_SCOPE_AGENT);
    } else {
        if (threadIdx.x == 0) {
            __hip_atomic_store(&bar[flg_off + lb*16], target, __ATOMIC_RELEASE,
                               __HIP_MEMORY_SCOPE_AGENT);
            while (__hip_atomic_load(&bar[gen_off], __ATOMIC_RELAXED,
                                     __HIP_MEMORY_SCOPE_AGENT) < target)
                __builtin_amdgcn_s_sleep(2);
            __builtin_amdgcn_fence(__ATOMIC_ACQUIRE, "agent");
        }
        __syncthreads();
    }
}

struct SimArgs {
    const float* v; const float* scat; const float* amp;
    const int* sloc; const int* rloc;
    float* out; float* ws;
};

// ================= persistent single-kernel path =================
__global__ __launch_bounds__(NTHR, 2) void k_sim(SimArgs A) {
    const int tid = blockIdx.x*NTHR + threadIdx.x;
    const int nth = NBLK*NTHR;
    const int s   = blockIdx.x / SBLK;          // shot partition
    const int lb  = blockIdx.x - s*SBLK;        // local block in partition
    const int lt  = lb*NTHR + threadIdx.x;      // local thread in partition
    const int lnt = SBLK*NTHR;

    unsigned* bar = (unsigned*)A.ws;
    unsigned* vmx = bar + VMXO;

    float* base = A.ws + BARF;
    const size_t F = (size_t)NTOT;
    float* wA   = base;
    float* wB   = wA + F;
    float* sA   = wB + F;
    float* sB   = sA + F;
    float* pxA  = sB + F;
    float* pxB  = pxA + PXSZ;
    float* pxsA = pxB + PXSZ;
    float* pxsB = pxsA + PXSZ;
    float* zx   = pxsB + PXSZ;
    float* zxs  = zx + PXSZ;
    float* pyA  = zxs + PXSZ;
    float* pyB  = pyA + PYSZ;
    float* pysA = pyB + PYSZ;
    float* pysB = pysA + PYSZ;
    float* zy   = pysB + PYSZ;
    float* zys  = zy + PYSZ;
    float* v2   = zys + PYSZ;
    float* st   = v2 + NCELL;
    float* axv  = st + NCELL;
    float* bxv  = axv + NX;
    float* ayv  = bxv + NX;
    float* byv  = ayv + NYW;

    // phase 0: zero recurrence state (barrier region zeroed by host memset)
    const size_t ZTOT = 4*F + 6*(size_t)PXSZ + 6*(size_t)PYSZ;
    for (size_t z = (size_t)tid; z < ZTOT; z += (size_t)nth) base[z] = 0.f;
    fbar(bar, GFLG, GGEN, blockIdx.x, NBLK, 1u);

    // phase 1: vmax
    {
        float m = 0.f;
        for (int idx = tid; idx < NZV*NYV; idx += nth) m = fmaxf(m, fabsf(A.v[idx]));
        __shared__ float sm[NTHR];
        sm[threadIdx.x] = m; __syncthreads();
        for (int o = NTHR/2; o > 0; o >>= 1) {
            if (threadIdx.x < o) sm[threadIdx.x] = fmaxf(sm[threadIdx.x], sm[threadIdx.x+o]);
            __syncthreads();
        }
        if (threadIdx.x == 0) atomicMax(vmx, __float_as_uint(sm[0]));
    }
    fbar(bar, GFLG, GGEN, blockIdx.x, NBLK, 2u);

    // phase 2: PML profiles + v2dt2/sterm
    {
        float vmax = __uint_as_float(__hip_atomic_load(vmx, __ATOMIC_RELAXED,
                                                       __HIP_MEMORY_SCOPE_AGENT));
        if (tid < NX) prof1(tid, NX, 5.0f, vmax, &axv[tid], &bxv[tid]);
        else if (tid < NX + NYW) { int y = tid - NX; prof1(y, NYW, 5.0f, vmax, &ayv[y], &byv[y]); }
        for (int c = tid; c < NCELL; c += nth) {
            int i = c / NYW, j = c - (c / NYW)*NYW;
            int iz = min(max(i - PADC, 0), NZV-1);
            int iy = min(max(j - PADC, 0), NYV-1);
            float vv = A.v[iz*NYV + iy];
            v2[c] = vv*vv*(DTF*DTF);
            float sp = 0.f;
            if (i >= PADC && i < PADC+NZV && j >= PADC && j < PADC+NYV)
                sp = A.scat[(i-PADC)*NYV + (j-PADC)];
            st[c] = 2.f*vv*sp*(DTF*DTF);
        }
    }
    fbar(bar, GFLG, GGEN, blockIdx.x, NBLK, 3u);

    // time loop: per-shot barriers (shots are independent)
    float *wcb=wA, *wpb=wB, *sccb=sA, *scpb=sB;
    float *pxc=pxA, *pxn=pxB, *pxsc=pxsA, *pxsn=pxsB;
    float *pyc=pyA, *pyn=pyB, *pysc=pysA, *pysn=pysB;

    const int sflg = SFLG + s*SSTR;
    const int sgen = SGEN + s*16;

    for (int t = 0; t < NTS; ++t) {
        for (int r = lt; r < NCELL; r += lnt)
            cell_update(s*NCELL + r, t, wcb, wpb, sccb, scpb,
                        pxc, pxn, pyc, pyn, pxsc, pxsn, pysc, pysn,
                        zx, zy, zxs, zys, v2, st, axv, bxv, ayv, byv,
                        A.amp, A.sloc);
        fbar(bar, sflg, sgen, lb, SBLK, (unsigned)(t+1));

        // gather: reads just-written scpb; next step only READS that buffer.
        if (lt < NRECV) {
            int ri = A.rloc[(s*NRECV+lt)*2+0] + PADC;
            int rj = A.rloc[(s*NRECV+lt)*2+1] + PADC;
            A.out[(s*NRECV+lt)*NTS + t] = ld3(&scpb[s*NCELL + ri*NYW + rj]);
        }

        float* tm;
        tm=wcb;  wcb=wpb;   wpb=tm;
        tm=sccb; sccb=scpb; scpb=tm;
        tm=pxc;  pxc=pxn;   pxn=tm;
        tm=pyc;  pyc=pyn;   pyn=tm;
        tm=pxsc; pxsc=pxsn; pxsn=tm;
        tm=pysc; pysc=pysn; pysn=tm;
    }
}

// ================= fallback multi-kernel path (verified round-2) =================
__global__ void k_vmax(const float* __restrict__ v, unsigned* __restrict__ vmx) {
    __shared__ float sm[256];
    float m = 0.f;
    for (int idx = blockIdx.x*256 + threadIdx.x; idx < NZV*NYV; idx += gridDim.x*256)
        m = fmaxf(m, fabsf(v[idx]));
    sm[threadIdx.x] = m; __syncthreads();
    for (int o = 128; o > 0; o >>= 1) {
        if (threadIdx.x < o) sm[threadIdx.x] = fmaxf(sm[threadIdx.x], sm[threadIdx.x+o]);
        __syncthreads();
    }
    if (threadIdx.x == 0) atomicMax(vmx, __float_as_uint(sm[0]));
}

__global__ void k_prep(const float* __restrict__ v, const float* __restrict__ sc,
                       float* __restrict__ v2dt2, float* __restrict__ sterm) {
    int c = blockIdx.x*blockDim.x + threadIdx.x;
    if (c >= NCELL) return;
    int i = c / NYW, j = c - (c / NYW)*NYW;
    int iz = min(max(i - PADC, 0), NZV-1);
    int iy = min(max(j - PADC, 0), NYV-1);
    float vv = v[iz*NYV + iy];
    v2dt2[c] = vv*vv*(DTF*DTF);
    float sp = 0.f;
    if (i >= PADC && i < PADC+NZV && j >= PADC && j < PADC+NYV)
        sp = sc[(i-PADC)*NYV + (j-PADC)];
    sterm[c] = 2.f*vv*sp*(DTF*DTF);
}

__global__ void k_prof(const unsigned* __restrict__ vmx,
                       float* __restrict__ axv, float* __restrict__ bxv,
                       float* __restrict__ ayv, float* __restrict__ byv) {
    int x = threadIdx.x;
    float vmax = __uint_as_float(vmx[0]);
    if (x < NX)  prof1(x, NX,  5.0f, vmax, &axv[x], &bxv[x]);
    if (x < NYW) prof1(x, NYW, 5.0f, vmax, &ayv[x], &byv[x]);
}

__global__ __launch_bounds__(256) void k_fstep(
    const float* __restrict__ wf,   float* __restrict__ wold,
    const float* __restrict__ wsf,  float* __restrict__ wsold,
    const float* __restrict__ pxo,  float* __restrict__ pxn,
    const float* __restrict__ pyo,  float* __restrict__ pyn,
    const float* __restrict__ pxso, float* __restrict__ pxsn,
    const float* __restrict__ pyso, float* __restrict__ pysn,
    float* __restrict__ zx,  float* __restrict__ zy,
    float* __restrict__ zxs, float* __restrict__ zys,
    const float* __restrict__ v2, const float* __restrict__ st,
    const float* __restrict__ axv, const float* __restrict__ bxv,
    const float* __restrict__ ayv, const float* __restrict__ byv,
    const float* __restrict__ amp, const int* __restrict__ sloc,
    const int* __restrict__ rloc, float* __restrict__ out, int t)
{
    int bid = blockIdx.x;
    if (bid >= NSB) {
        if (t == 0) return;
        int g = (bid - NSB)*256 + threadIdx.x;
        if (g >= NSHOT*NRECV) return;
        int s = g / NRECV, rr = g - s*NRECV;
        int ri = rloc[(s*NRECV+rr)*2+0] + PADC;
        int rj = rloc[(s*NRECV+rr)*2+1] + PADC;
        out[(s*NRECV+rr)*NTS + (t-1)] = wsf[s*NCELL + ri*NYW + rj];
        return;
    }
    int c = bid*256 + threadIdx.x;
    if (c >= NTOT) return;
    cell_update(c, t, wf, wold, wsf, wsold,
                pxo, pxn, pyo, pyn, pxso, pxsn, pyso, pysn,
                zx, zy, zxs, zys, v2, st, axv, bxv, ayv, byv, amp, sloc);
}

__global__ void k_gtail(const float* __restrict__ wsn, const int* __restrict__ rloc,
                        float* __restrict__ out) {
    int g = blockIdx.x*blockDim.x + threadIdx.x;
    if (g >= NSHOT*NRECV) return;
    int s = g / NRECV, rr = g - s*NRECV;
    int ri = rloc[(s*NRECV+rr)*2+0] + PADC;
    int rj = rloc[(s*NRECV+rr)*2+1] + PADC;
    out[(s*NRECV+rr)*NTS + (NTS-1)] = wsn[s*NCELL + ri*NYW + rj];
}

extern "C" void kernel_launch(void* const* d_in, const int* in_sizes, int n_in,
                              void* d_out, int out_size, void* d_ws, size_t ws_size,
                              hipStream_t stream) {
    const float* v    = (const float*)d_in[0];
    const float* scat = (const float*)d_in[1];
    const float* amp  = (const float*)d_in[2];
    const int*   sloc = (const int*)d_in[3];
    const int*   rloc = (const int*)d_in[4];
    float* out = (float*)d_out;
    float* ws  = (float*)d_ws;

    SimArgs args;
    args.v = v; args.scat = scat; args.amp = amp;
    args.sloc = sloc; args.rloc = rloc;
    args.out = out; args.ws = ws;

    // zero barrier flags + gens + vmax accumulator
    hipMemsetAsync(ws, 0, BARF*sizeof(float), stream);

    void* kargs[] = { &args };
    hipError_t e = hipLaunchCooperativeKernel((const void*)k_sim, dim3(NBLK), dim3(NTHR),
                                              kargs, 0, stream);
    if (e == hipSuccess) return;

    // ---- fallback: verified multi-kernel path
    float* base = ws + BARF;
    const size_t F = (size_t)NTOT;
    float* wA   = base;
    float* wB   = wA + F;
    float* sA   = wB + F;
    float* sB   = sA + F;
    float* pxA  = sB + F;
    float* pxB  = pxA + PXSZ;
    float* pxsA = pxB + PXSZ;
    float* pxsB = pxsA + PXSZ;
    float* zx   = pxsB + PXSZ;
    float* zxs  = zx + PXSZ;
    float* pyA  = zxs + PXSZ;
    float* pyB  = pyA + PYSZ;
    float* pysA = pyB + PYSZ;
    float* pysB = pysA + PYSZ;
    float* zy   = pysB + PYSZ;
    float* zys  = zy + PYSZ;
    float* v2   = zys + PYSZ;
    float* st   = v2 + NCELL;
    float* axv  = st + NCELL;
    float* bxv  = axv + NX;
    float* ayv  = bxv + NX;
    float* byv  = ayv + NYW;
    unsigned* vmx = (unsigned*)ws + VMXO;

    size_t zero_floats = 4*F + 6*(size_t)PXSZ + 6*(size_t)PYSZ;
    hipMemsetAsync(base, 0, zero_floats*sizeof(float), stream);

    hipLaunchKernelGGL(k_vmax, dim3(64), dim3(256), 0, stream, v, vmx);
    hipLaunchKernelGGL(k_prep, dim3((NCELL+255)/256), dim3(256), 0, stream, v, scat, v2, st);
    hipLaunchKernelGGL(k_prof, dim3(1), dim3(512), 0, stream, vmx, axv, bxv, ayv, byv);

    float* wc  = wA;  float* wp  = wB;
    float* scc = sA;  float* scp = sB;
    float* pxc = pxA; float* pxn = pxB;
    float* pyc = pyA; float* pyn = pyB;
    float* pxsc = pxsA; float* pxsn = pxsB;
    float* pysc = pysA; float* pysn = pysB;

    for (int t = 0; t < NTS; ++t) {
        hipLaunchKernelGGL(k_fstep, dim3(NSB + GB), dim3(256), 0, stream,
                           wc, wp, scc, scp,
                           pxc, pxn, pyc, pyn, pxsc, pxsn, pysc, pysn,
                           zx, zy, zxs, zys,
                           v2, st, axv, bxv, ayv, byv,
                           amp, sloc, rloc, out, t);
        float* tmp;
        tmp = wc;  wc  = wp;  wp  = tmp;
        tmp = scc; scc = scp; scp = tmp;
        tmp = pxc; pxc = pxn; pxn = tmp;
        tmp = pyc; pyc = pyn; pyn = tmp;
        tmp = pxsc; pxsc = pxsn; pxsn = tmp;
        tmp = pysc; pysc = pysn; pysn = tmp;
    }
    hipLaunchKernelGGL(k_gtail, dim3(2), dim3(256), 0, stream, scc, rloc, out);
}